// Round 3
// baseline (573.354 us; speedup 1.0000x reference)
//
#include <hip/hip_runtime.h>
#include <stdint.h>

// MHA: B=4, S=2048, D=1024, H=16, HD=64.
// Pipeline: f32->bf16 cvt -> fused QKV GEMM (bf16 MFMA) -> flash attn (32x32 bf16
// MFMA, fp32 online softmax, fully in-register P) -> output GEMM (bf16 MFMA, fp32).
// Q is pre-scaled by 0.125*log2(e) so softmax uses exp2 directly (exact semantics).

typedef __bf16 bf16x8 __attribute__((ext_vector_type(8)));
typedef float f32x4 __attribute__((ext_vector_type(4)));
typedef float f32x16 __attribute__((ext_vector_type(16)));

__device__ __forceinline__ uint16_t f2bf(float f) {
  union { float f; uint32_t u; } c;
  c.f = f;
  uint32_t u = c.u + 0x7fffu + ((c.u >> 16) & 1u);  // RNE
  return (uint16_t)(u >> 16);
}

__device__ __forceinline__ float exp2_hw(float x) {
#if defined(__has_builtin) && __has_builtin(__builtin_amdgcn_exp2f)
  return __builtin_amdgcn_exp2f(x);
#else
  return exp2f(x);
#endif
}

__device__ __forceinline__ uint32_t cvt_pk_bf16(float lo, float hi) {
  uint32_t r;
  asm("v_cvt_pk_bf16_f32 %0, %1, %2" : "=v"(r) : "v"(lo), "v"(hi));
  return r;
}

__device__ __forceinline__ void gload16(const void* g, void* l) {
  __builtin_amdgcn_global_load_lds(
      (const __attribute__((address_space(1))) uint32_t*)g,
      (__attribute__((address_space(3))) uint32_t*)l,
      16, 0, 0);
}

__global__ void cvt_f32_bf16(const float* __restrict__ in,
                             uint16_t* __restrict__ out, int n4) {
  int i = blockIdx.x * blockDim.x + threadIdx.x;
  if (i >= n4) return;
  float4 v = reinterpret_cast<const float4*>(in)[i];
  union { uint16_t u[4]; uint2 d; } o;
  o.u[0] = f2bf(v.x); o.u[1] = f2bf(v.y);
  o.u[2] = f2bf(v.z); o.u[3] = f2bf(v.w);
  reinterpret_cast<uint2*>(out)[i] = o.d;
}

// C[m,n] = sum_k A[m,k] * W[n,k] + bias  (torch Linear). A,W bf16 row-major K=1024.
// MODE 0: QKV fused (N=3072, weight/bias selected per 1024-col group).
//   q -> oq[bh][s][hd] bf16, scaled by 0.125*log2e; k -> ok[bh][s][hd]; v -> ovT[bh][hd][s].
// MODE 1: out-proj (N=1024), writes fp32 ofp[m][n].
template <int MODE>
__global__ __launch_bounds__(256, 2)
void gemm_nt(const uint16_t* __restrict__ A,
             const uint16_t* __restrict__ W0, const uint16_t* __restrict__ W1,
             const uint16_t* __restrict__ W2,
             const float* __restrict__ b0, const float* __restrict__ b1,
             const float* __restrict__ b2,
             uint16_t* __restrict__ oq, uint16_t* __restrict__ ok2,
             uint16_t* __restrict__ ovT, float* __restrict__ ofp) {
  __shared__ __align__(16) uint16_t Alds[2][128 * 32];
  __shared__ __align__(16) uint16_t Blds[2][128 * 32];

  const int tid = threadIdx.x;
  const int w = tid >> 6;
  const int l = tid & 63;
  const int wm = w >> 1, wn = w & 1;
  const int g = l >> 4, c16 = l & 15;
  const int brow = blockIdx.y * 128;
  const int bcol = blockIdx.x * 128;

  const uint16_t* Wsel = W0;
  const float* bsel = b0;
  if (MODE == 0) {
    const int which = bcol >> 10;
    Wsel = (which == 0) ? W0 : ((which == 1) ? W1 : W2);
    bsel = (which == 0) ? b0 : ((which == 1) ? b1 : b2);
  }
  const int bw = bcol & 1023;

  const int srow = l >> 2;         // staging: row-within-16 (chunk c adds c*16)
  const int scol = (l & 3) * 8;    // staging: col (8 bf16 = 16B per lane)

  f32x4 acc[4][4];
#pragma unroll
  for (int i = 0; i < 4; ++i)
#pragma unroll
    for (int j = 0; j < 4; ++j) acc[i][j] = {0.f, 0.f, 0.f, 0.f};

  // prologue stage kt=0 into buf 0
#pragma unroll
  for (int i2 = 0; i2 < 2; ++i2) {
    const int c = 2 * w + i2;
    gload16(A + (size_t)(brow + c * 16 + srow) * 1024 + scol, &Alds[0][c * 512]);
    gload16(Wsel + (size_t)(bw + c * 16 + srow) * 1024 + scol, &Blds[0][c * 512]);
  }

  for (int kt = 0; kt < 32; ++kt) {
    __syncthreads();  // buf[kt&1] staged; all waves done reading buf[(kt+1)&1]
    const int cur = kt & 1;
    if (kt + 1 < 32) {
      const int k0 = (kt + 1) * 32;
#pragma unroll
      for (int i2 = 0; i2 < 2; ++i2) {
        const int c = 2 * w + i2;
        gload16(A + (size_t)(brow + c * 16 + srow) * 1024 + k0 + scol,
                &Alds[cur ^ 1][c * 512]);
        gload16(Wsel + (size_t)(bw + c * 16 + srow) * 1024 + k0 + scol,
                &Blds[cur ^ 1][c * 512]);
      }
    }
    bf16x8 af[4], bfr[4];
#pragma unroll
    for (int i = 0; i < 4; ++i)
      af[i] = *reinterpret_cast<const bf16x8*>(
          &Alds[cur][(wm * 64 + i * 16 + c16) * 32 + g * 8]);
#pragma unroll
    for (int j = 0; j < 4; ++j)
      bfr[j] = *reinterpret_cast<const bf16x8*>(
          &Blds[cur][(wn * 64 + j * 16 + c16) * 32 + g * 8]);
#pragma unroll
    for (int i = 0; i < 4; ++i)
#pragma unroll
      for (int j = 0; j < 4; ++j)
        acc[i][j] = __builtin_amdgcn_mfma_f32_16x16x32_bf16(af[i], bfr[j],
                                                            acc[i][j], 0, 0, 0);
  }

  // epilogue: D row = 4*(l>>4)+reg, col = l&15 (m89-verified)
#pragma unroll
  for (int i = 0; i < 4; ++i) {
#pragma unroll
    for (int j = 0; j < 4; ++j) {
      const int n = bcol + wn * 64 + j * 16 + c16;
      const int nn = n & 1023;
      const float bias = bsel[nn];
#pragma unroll
      for (int r = 0; r < 4; ++r) {
        const int m = brow + wm * 64 + i * 16 + g * 4 + r;
        const float val = acc[i][j][r] + bias;
        if (MODE == 0) {
          const int which = n >> 10;
          const int s = m & 2047, b = m >> 11;
          const int h = nn >> 6, hd = nn & 63;
          const size_t bh = (size_t)(b * 16 + h);
          if (which == 0)
            oq[(bh * 2048 + s) * 64 + hd] = f2bf(val * 0.18033688011112042f);
          else if (which == 1)
            ok2[(bh * 2048 + s) * 64 + hd] = f2bf(val);
          else
            ovT[(bh * 64 + hd) * 2048 + s] = f2bf(val);
        } else {
          ofp[(size_t)m * 1024 + n] = val;
        }
      }
    }
  }
}

// Flash attention, 32x32 MFMA swapped-operand form. Grid (bh=64, qb=8), 4 waves,
// wave owns 64 q-rows (2 groups of 32). Per 64-key tile: K-frags (8 b128) and
// V-frags (8 b128) register-shared across both q-groups -> 32 MFMA(32x32x16)
// per 16 LDS reads. Lane (q5=l&31, hi=l>>5) owns q-row q5 of each group, half
// the keys. A-row key-permutation kappa (bit swap 2<->3) makes each lane's 16
// score regs exactly its PV B-fragment keys, in register order.
__global__ __launch_bounds__(256, 3)
void attn_fwd(const uint16_t* __restrict__ Q, const uint16_t* __restrict__ K,
              const uint16_t* __restrict__ VT, uint16_t* __restrict__ CTX) {
  __shared__ __align__(16) uint16_t Klds[2][64 * 64];
  __shared__ __align__(16) uint16_t Vlds[2][64 * 64];

  const int tid = threadIdx.x;
  const int w = tid >> 6;
  const int l = tid & 63;
  const int hi = l >> 5, q5 = l & 31;
  const int bh = blockIdx.x;
  const int qb = blockIdx.y;
  const int qrow_base = qb * 256 + w * 64;

  // kappa: D-row r holds key kappa(r); bijective bit-swap of bits 2 and 3
  const int kappa = (q5 & 3) | (((q5 >> 3) & 1) << 2) | (((q5 >> 2) & 1) << 3) |
                    ((q5 >> 4) << 4);

  // Q fragments: B-operand cols = q5, k = 8*hi + j at hd-chunk 16*ks
  bf16x8 qf[2][4];
#pragma unroll
  for (int grp = 0; grp < 2; ++grp) {
    const uint16_t* qp =
        Q + ((size_t)bh * 2048 + qrow_base + grp * 32 + q5) * 64 + 8 * hi;
#pragma unroll
    for (int ks = 0; ks < 4; ++ks)
      qf[grp][ks] = *reinterpret_cast<const bf16x8*>(qp + 16 * ks);
  }

  f32x16 ctx[2][2];  // [grp][hd-block]
#pragma unroll
  for (int grp = 0; grp < 2; ++grp)
#pragma unroll
    for (int hb = 0; hb < 2; ++hb)
#pragma unroll
      for (int e = 0; e < 16; ++e) ctx[grp][hb][e] = 0.f;
  float M[2] = {-1024.0f, -1024.0f};  // finite sentinel -> first tile rescales
  float L[2] = {0.f, 0.f};

  auto stage = [&](int kt, int buf) {
#pragma unroll
    for (int i2 = 0; i2 < 2; ++i2) {
      const int c = 2 * w + i2;
      const int lb = c * 1024 + l * 16;          // linear dest byte in 8KB tile
      const int row = lb >> 7;                   // 128B rows
      const int so = lb ^ ((row & 7) << 4);      // inverse-swizzled source byte
      const int colel = (so & 127) >> 1;
      gload16(K + ((size_t)bh * 2048 + kt * 64 + row) * 64 + colel,
              &Klds[buf][c * 512]);
      gload16(VT + ((size_t)bh * 64 + row) * 2048 + kt * 64 + colel,
              &Vlds[buf][c * 512]);
    }
  };

  // precomputed swizzled in-row byte offsets
  int koff[4], voff[2][2];  // koff[ks]; voff[half][ks2]
#pragma unroll
  for (int ks = 0; ks < 4; ++ks)
    koff[ks] = (32 * ks + 16 * hi) ^ ((kappa & 7) << 4);
#pragma unroll
  for (int half = 0; half < 2; ++half)
#pragma unroll
    for (int ks2 = 0; ks2 < 2; ++ks2)
      voff[half][ks2] = (half * 64 + 32 * ks2 + 16 * hi) ^ ((q5 & 7) << 4);

  stage(0, 0);

  for (int kt = 0; kt < 32; ++kt) {
    __syncthreads();
    const int cur = kt & 1;
    if (kt + 1 < 32) stage(kt + 1, cur ^ 1);
    const uint8_t* kb = reinterpret_cast<const uint8_t*>(&Klds[cur][0]);
    const uint8_t* vb = reinterpret_cast<const uint8_t*>(&Vlds[cur][0]);

#pragma unroll
    for (int half = 0; half < 2; ++half) {
      // K A-frags: row = half*32 + kappa, 4 hd-chunks
      bf16x8 kf[4];
      const int krow = half * 32 + kappa;
#pragma unroll
      for (int ks = 0; ks < 4; ++ks)
        kf[ks] = *reinterpret_cast<const bf16x8*>(kb + krow * 128 + koff[ks]);
      // V A-frags: row = 32*hb + q5, keys 16*ks2(+half*32)
      bf16x8 vf[2][2];
#pragma unroll
      for (int hb = 0; hb < 2; ++hb) {
        const int vrow = 32 * hb + q5;
#pragma unroll
        for (int ks2 = 0; ks2 < 2; ++ks2)
          vf[hb][ks2] = *reinterpret_cast<const bf16x8*>(
              vb + vrow * 128 + voff[half][ks2]);
      }

#pragma unroll
      for (int grp = 0; grp < 2; ++grp) {
        // QK^T: D[key32][q32], C-init = -M folds running-max subtraction
        const float negM = -M[grp];
        f32x16 sc;
#pragma unroll
        for (int e = 0; e < 16; ++e) sc[e] = negM;
        __builtin_amdgcn_s_setprio(1);
#pragma unroll
        for (int ks = 0; ks < 4; ++ks)
          sc = __builtin_amdgcn_mfma_f32_32x32x16_bf16(kf[ks], qf[grp][ks], sc,
                                                       0, 0, 0);
        __builtin_amdgcn_s_setprio(0);

        // row max: 15 in-lane + 1 cross (lane pair l <-> l+32)
        float m0 = fmaxf(fmaxf(sc[0], sc[1]), fmaxf(sc[2], sc[3]));
        float m1 = fmaxf(fmaxf(sc[4], sc[5]), fmaxf(sc[6], sc[7]));
        float m2 = fmaxf(fmaxf(sc[8], sc[9]), fmaxf(sc[10], sc[11]));
        float m3 = fmaxf(fmaxf(sc[12], sc[13]), fmaxf(sc[14], sc[15]));
        float mloc = fmaxf(fmaxf(m0, m1), fmaxf(m2, m3));
        mloc = fmaxf(mloc, __shfl_xor(mloc, 32));

        float p[16];
        if (__any(mloc > 8.0f)) {  // defer-max: rescale only on >2^8 growth
          const float delta = fmaxf(mloc, 0.0f);
          const float corr = exp2_hw(-delta);
          M[grp] += delta;
          L[grp] *= corr;
#pragma unroll
          for (int hb = 0; hb < 2; ++hb)
#pragma unroll
            for (int e = 0; e < 16; ++e) ctx[grp][hb][e] *= corr;
#pragma unroll
          for (int e = 0; e < 16; ++e) p[e] = exp2_hw(sc[e] - delta);
        } else {
#pragma unroll
          for (int e = 0; e < 16; ++e) p[e] = exp2_hw(sc[e]);
        }

        L[grp] += ((p[0] + p[1]) + (p[2] + p[3])) +
                  ((p[4] + p[5]) + (p[6] + p[7])) +
                  ((p[8] + p[9]) + (p[10] + p[11])) +
                  ((p[12] + p[13]) + (p[14] + p[15]));

        // pack P: reg r <-> key 16*(r>>3) + 8*hi + (r&7), already B-frag order
        union { uint32_t u[4]; bf16x8 v; } pa0, pa1;
        pa0.u[0] = cvt_pk_bf16(p[0], p[1]);
        pa0.u[1] = cvt_pk_bf16(p[2], p[3]);
        pa0.u[2] = cvt_pk_bf16(p[4], p[5]);
        pa0.u[3] = cvt_pk_bf16(p[6], p[7]);
        pa1.u[0] = cvt_pk_bf16(p[8], p[9]);
        pa1.u[1] = cvt_pk_bf16(p[10], p[11]);
        pa1.u[2] = cvt_pk_bf16(p[12], p[13]);
        pa1.u[3] = cvt_pk_bf16(p[14], p[15]);

        __builtin_amdgcn_s_setprio(1);
#pragma unroll
        for (int hb = 0; hb < 2; ++hb) {
          ctx[grp][hb] = __builtin_amdgcn_mfma_f32_32x32x16_bf16(
              vf[hb][0], pa0.v, ctx[grp][hb], 0, 0, 0);
          ctx[grp][hb] = __builtin_amdgcn_mfma_f32_32x32x16_bf16(
              vf[hb][1], pa1.v, ctx[grp][hb], 0, 0, 0);
        }
        __builtin_amdgcn_s_setprio(0);
      }
    }
  }

  // finalize: L reduce across lane pair, normalize, store
  const int b = bh >> 4, h = bh & 15;
#pragma unroll
  for (int grp = 0; grp < 2; ++grp) {
    float Lt = L[grp] + __shfl_xor(L[grp], 32);
    const float inv = 1.0f / Lt;
    const int s = qrow_base + grp * 32 + q5;
#pragma unroll
    for (int hb = 0; hb < 2; ++hb) {
#pragma unroll
      for (int t = 0; t < 4; ++t) {
        // regs 4t..4t+3 -> hd = 32*hb + 8*t + 4*hi + (0..3)
        uint2 st;
        st.x = cvt_pk_bf16(ctx[grp][hb][4 * t] * inv,
                           ctx[grp][hb][4 * t + 1] * inv);
        st.y = cvt_pk_bf16(ctx[grp][hb][4 * t + 2] * inv,
                           ctx[grp][hb][4 * t + 3] * inv);
        *reinterpret_cast<uint2*>(
            &CTX[((size_t)b * 2048 + s) * 1024 + h * 64 + hb * 32 + t * 8 +
                 hi * 4]) = st;
      }
    }
  }
}

extern "C" void kernel_launch(void* const* d_in, const int* in_sizes, int n_in,
                              void* d_out, int out_size, void* d_ws,
                              size_t ws_size, hipStream_t stream) {
  (void)in_sizes; (void)n_in; (void)out_size; (void)ws_size;
  const float* x = (const float*)d_in[0];
  const float* wq = (const float*)d_in[1];
  const float* bq = (const float*)d_in[2];
  const float* wk = (const float*)d_in[3];
  const float* bk = (const float*)d_in[4];
  const float* wv = (const float*)d_in[5];
  const float* bv = (const float*)d_in[6];
  const float* wo = (const float*)d_in[7];
  const float* bo = (const float*)d_in[8];
  float* out = (float*)d_out;

  // ws layout (88 MB total)
  uint8_t* ws = (uint8_t*)d_ws;
  uint16_t* xb   = (uint16_t*)(ws + 0);                       // 16 MB  x bf16 [8192][1024]
  uint16_t* wqb  = (uint16_t*)(ws + 16777216);                // 2 MB each
  uint16_t* wkb  = (uint16_t*)(ws + 16777216 + 2097152);
  uint16_t* wvb  = (uint16_t*)(ws + 16777216 + 2 * 2097152);
  uint16_t* wob  = (uint16_t*)(ws + 16777216 + 3 * 2097152);
  uint16_t* qws  = (uint16_t*)(ws + 25165824);                // 16 MB [bh][s][hd]
  uint16_t* kws  = (uint16_t*)(ws + 25165824 + 16777216);     // 16 MB [bh][s][hd]
  uint16_t* vtws = (uint16_t*)(ws + 25165824 + 2 * 16777216); // 16 MB [bh][hd][s]
  uint16_t* ctxw = (uint16_t*)(ws + 25165824 + 3 * 16777216); // 16 MB [b][s][1024]

  cvt_f32_bf16<<<8192, 256, 0, stream>>>(x, xb, 2097152);
  cvt_f32_bf16<<<1024, 256, 0, stream>>>(wq, wqb, 262144);
  cvt_f32_bf16<<<1024, 256, 0, stream>>>(wk, wkb, 262144);
  cvt_f32_bf16<<<1024, 256, 0, stream>>>(wv, wvb, 262144);
  cvt_f32_bf16<<<1024, 256, 0, stream>>>(wo, wob, 262144);

  gemm_nt<0><<<dim3(24, 64), 256, 0, stream>>>(
      xb, wqb, wkb, wvb, bq, bk, bv, qws, kws, vtws, nullptr);
  attn_fwd<<<dim3(64, 8), 256, 0, stream>>>(qws, kws, vtws, ctxw);
  gemm_nt<1><<<dim3(8, 64), 256, 0, stream>>>(
      ctxw, wob, nullptr, nullptr, bo, nullptr, nullptr, nullptr, nullptr,
      nullptr, out);
}

// Round 5
// 234.845 us; speedup vs baseline: 2.4414x; 2.4414x over previous
//
#include <hip/hip_runtime.h>
#include <stdint.h>

// MHA: B=4, S=2048, D=1024, H=16, HD=64.
// Pipeline: f32->bf16 cvt -> fused QKV GEMM (bf16 MFMA) -> flash attn (32x32 bf16
// MFMA, fp32 online softmax, fully in-register P) -> output GEMM (bf16 MFMA, fp32).
// Q is pre-scaled by 0.125*log2(e) so softmax uses exp2 directly (exact semantics).

typedef __bf16 bf16x8 __attribute__((ext_vector_type(8)));
typedef float f32x4 __attribute__((ext_vector_type(4)));
typedef float f32x16 __attribute__((ext_vector_type(16)));

__device__ __forceinline__ uint16_t f2bf(float f) {
  union { float f; uint32_t u; } c;
  c.f = f;
  uint32_t u = c.u + 0x7fffu + ((c.u >> 16) & 1u);  // RNE
  return (uint16_t)(u >> 16);
}

__device__ __forceinline__ float exp2_hw(float x) {
#if defined(__has_builtin) && __has_builtin(__builtin_amdgcn_exp2f)
  return __builtin_amdgcn_exp2f(x);
#else
  return exp2f(x);
#endif
}

__device__ __forceinline__ uint32_t cvt_pk_bf16(float lo, float hi) {
  uint32_t r;
  asm("v_cvt_pk_bf16_f32 %0, %1, %2" : "=v"(r) : "v"(lo), "v"(hi));
  return r;
}

__device__ __forceinline__ void gload16(const void* g, void* l) {
  __builtin_amdgcn_global_load_lds(
      (const __attribute__((address_space(1))) uint32_t*)g,
      (__attribute__((address_space(3))) uint32_t*)l,
      16, 0, 0);
}

__global__ void cvt_f32_bf16(const float* __restrict__ in,
                             uint16_t* __restrict__ out, int n4) {
  int i = blockIdx.x * blockDim.x + threadIdx.x;
  if (i >= n4) return;
  float4 v = reinterpret_cast<const float4*>(in)[i];
  union { uint16_t u[4]; uint2 d; } o;
  o.u[0] = f2bf(v.x); o.u[1] = f2bf(v.y);
  o.u[2] = f2bf(v.z); o.u[3] = f2bf(v.w);
  reinterpret_cast<uint2*>(out)[i] = o.d;
}

// C[m,n] = sum_k A[m,k] * W[n,k] + bias  (torch Linear). A,W bf16 row-major K=1024.
// MODE 0: QKV fused (N=3072, weight/bias selected per 1024-col group).
//   q -> oq[bh][s][hd] bf16, scaled by 0.125*log2e; k -> ok[bh][s][hd]; v -> ovT[bh][hd][s].
// MODE 1: out-proj (N=1024), writes fp32 ofp[m][n].
template <int MODE>
__global__ __launch_bounds__(256, 2)
void gemm_nt(const uint16_t* __restrict__ A,
             const uint16_t* __restrict__ W0, const uint16_t* __restrict__ W1,
             const uint16_t* __restrict__ W2,
             const float* __restrict__ b0, const float* __restrict__ b1,
             const float* __restrict__ b2,
             uint16_t* __restrict__ oq, uint16_t* __restrict__ ok2,
             uint16_t* __restrict__ ovT, float* __restrict__ ofp) {
  __shared__ __align__(16) uint16_t Alds[2][128 * 32];
  __shared__ __align__(16) uint16_t Blds[2][128 * 32];

  const int tid = threadIdx.x;
  const int w = tid >> 6;
  const int l = tid & 63;
  const int wm = w >> 1, wn = w & 1;
  const int g = l >> 4, c16 = l & 15;
  const int brow = blockIdx.y * 128;
  const int bcol = blockIdx.x * 128;

  const uint16_t* Wsel = W0;
  const float* bsel = b0;
  if (MODE == 0) {
    const int which = bcol >> 10;
    Wsel = (which == 0) ? W0 : ((which == 1) ? W1 : W2);
    bsel = (which == 0) ? b0 : ((which == 1) ? b1 : b2);
  }
  const int bw = bcol & 1023;

  const int srow = l >> 2;         // staging: row-within-16 (chunk c adds c*16)
  const int scol = (l & 3) * 8;    // staging: col (8 bf16 = 16B per lane)

  f32x4 acc[4][4];
#pragma unroll
  for (int i = 0; i < 4; ++i)
#pragma unroll
    for (int j = 0; j < 4; ++j) acc[i][j] = {0.f, 0.f, 0.f, 0.f};

  // prologue stage kt=0 into buf 0
#pragma unroll
  for (int i2 = 0; i2 < 2; ++i2) {
    const int c = 2 * w + i2;
    gload16(A + (size_t)(brow + c * 16 + srow) * 1024 + scol, &Alds[0][c * 512]);
    gload16(Wsel + (size_t)(bw + c * 16 + srow) * 1024 + scol, &Blds[0][c * 512]);
  }

  for (int kt = 0; kt < 32; ++kt) {
    __syncthreads();  // buf[kt&1] staged; all waves done reading buf[(kt+1)&1]
    const int cur = kt & 1;
    if (kt + 1 < 32) {
      const int k0 = (kt + 1) * 32;
#pragma unroll
      for (int i2 = 0; i2 < 2; ++i2) {
        const int c = 2 * w + i2;
        gload16(A + (size_t)(brow + c * 16 + srow) * 1024 + k0 + scol,
                &Alds[cur ^ 1][c * 512]);
        gload16(Wsel + (size_t)(bw + c * 16 + srow) * 1024 + k0 + scol,
                &Blds[cur ^ 1][c * 512]);
      }
    }
    bf16x8 af[4], bfr[4];
#pragma unroll
    for (int i = 0; i < 4; ++i)
      af[i] = *reinterpret_cast<const bf16x8*>(
          &Alds[cur][(wm * 64 + i * 16 + c16) * 32 + g * 8]);
#pragma unroll
    for (int j = 0; j < 4; ++j)
      bfr[j] = *reinterpret_cast<const bf16x8*>(
          &Blds[cur][(wn * 64 + j * 16 + c16) * 32 + g * 8]);
#pragma unroll
    for (int i = 0; i < 4; ++i)
#pragma unroll
      for (int j = 0; j < 4; ++j)
        acc[i][j] = __builtin_amdgcn_mfma_f32_16x16x32_bf16(af[i], bfr[j],
                                                            acc[i][j], 0, 0, 0);
  }

  // epilogue: D row = 4*(l>>4)+reg, col = l&15 (m89-verified)
#pragma unroll
  for (int i = 0; i < 4; ++i) {
#pragma unroll
    for (int j = 0; j < 4; ++j) {
      const int n = bcol + wn * 64 + j * 16 + c16;
      const int nn = n & 1023;
      const float bias = bsel[nn];
#pragma unroll
      for (int r = 0; r < 4; ++r) {
        const int m = brow + wm * 64 + i * 16 + g * 4 + r;
        const float val = acc[i][j][r] + bias;
        if (MODE == 0) {
          const int which = n >> 10;
          const int s = m & 2047, b = m >> 11;
          const int h = nn >> 6, hd = nn & 63;
          const size_t bh = (size_t)(b * 16 + h);
          if (which == 0)
            oq[(bh * 2048 + s) * 64 + hd] = f2bf(val * 0.18033688011112042f);
          else if (which == 1)
            ok2[(bh * 2048 + s) * 64 + hd] = f2bf(val);
          else
            ovT[(bh * 64 + hd) * 2048 + s] = f2bf(val);
        } else {
          ofp[(size_t)m * 1024 + n] = val;
        }
      }
    }
  }
}

// Flash attention, 32x32 MFMA swapped-operand form. Grid (bh=64, qb=8), 4 waves,
// wave owns 64 q-rows (2 groups of 32). Per 64-key tile: K-frags (8 b128) and
// V-frags (8 b128) register-shared across both q-groups -> 32 MFMA(32x32x16)
// per 16 LDS reads. Lane (q5=l&31, hi=l>>5) owns q-row q5 of each group, half
// the keys. A-row key-permutation kappa (bit swap 2<->3) makes each lane's 16
// score regs exactly its PV B-fragment keys, in register order.
//
// HISTORY: R2 = this exact body w/ (256,3): PASSED but spilled (VGPR=84,
// 471MB scratch -> 454us). R3 = (256,2) + in-place exp2 over sc: NaN (codegen
// artifact). R4 = R2 body VERBATIM (separate p[16]) + (256,2) only: isolates
// the launch-bounds variable while removing the spill.
__global__ __launch_bounds__(256, 2)
void attn_fwd(const uint16_t* __restrict__ Q, const uint16_t* __restrict__ K,
              const uint16_t* __restrict__ VT, uint16_t* __restrict__ CTX) {
  __shared__ __align__(16) uint16_t Klds[2][64 * 64];
  __shared__ __align__(16) uint16_t Vlds[2][64 * 64];

  const int tid = threadIdx.x;
  const int w = tid >> 6;
  const int l = tid & 63;
  const int hi = l >> 5, q5 = l & 31;
  const int bh = blockIdx.x;
  const int qb = blockIdx.y;
  const int qrow_base = qb * 256 + w * 64;

  // kappa: D-row r holds key kappa(r); bijective bit-swap of bits 2 and 3
  const int kappa = (q5 & 3) | (((q5 >> 3) & 1) << 2) | (((q5 >> 2) & 1) << 3) |
                    ((q5 >> 4) << 4);

  // Q fragments: B-operand cols = q5, k = 8*hi + j at hd-chunk 16*ks
  bf16x8 qf[2][4];
#pragma unroll
  for (int grp = 0; grp < 2; ++grp) {
    const uint16_t* qp =
        Q + ((size_t)bh * 2048 + qrow_base + grp * 32 + q5) * 64 + 8 * hi;
#pragma unroll
    for (int ks = 0; ks < 4; ++ks)
      qf[grp][ks] = *reinterpret_cast<const bf16x8*>(qp + 16 * ks);
  }

  f32x16 ctx[2][2];  // [grp][hd-block]
#pragma unroll
  for (int grp = 0; grp < 2; ++grp)
#pragma unroll
    for (int hb = 0; hb < 2; ++hb)
#pragma unroll
      for (int e = 0; e < 16; ++e) ctx[grp][hb][e] = 0.f;
  float M[2] = {-1024.0f, -1024.0f};  // finite sentinel -> first tile rescales
  float L[2] = {0.f, 0.f};

  auto stage = [&](int kt, int buf) {
#pragma unroll
    for (int i2 = 0; i2 < 2; ++i2) {
      const int c = 2 * w + i2;
      const int lb = c * 1024 + l * 16;          // linear dest byte in 8KB tile
      const int row = lb >> 7;                   // 128B rows
      const int so = lb ^ ((row & 7) << 4);      // inverse-swizzled source byte
      const int colel = (so & 127) >> 1;
      gload16(K + ((size_t)bh * 2048 + kt * 64 + row) * 64 + colel,
              &Klds[buf][c * 512]);
      gload16(VT + ((size_t)bh * 64 + row) * 2048 + kt * 64 + colel,
              &Vlds[buf][c * 512]);
    }
  };

  // precomputed swizzled in-row byte offsets
  int koff[4], voff[2][2];  // koff[ks]; voff[half][ks2]
#pragma unroll
  for (int ks = 0; ks < 4; ++ks)
    koff[ks] = (32 * ks + 16 * hi) ^ ((kappa & 7) << 4);
#pragma unroll
  for (int half = 0; half < 2; ++half)
#pragma unroll
    for (int ks2 = 0; ks2 < 2; ++ks2)
      voff[half][ks2] = (half * 64 + 32 * ks2 + 16 * hi) ^ ((q5 & 7) << 4);

  stage(0, 0);

  for (int kt = 0; kt < 32; ++kt) {
    __syncthreads();
    const int cur = kt & 1;
    if (kt + 1 < 32) stage(kt + 1, cur ^ 1);
    const uint8_t* kb = reinterpret_cast<const uint8_t*>(&Klds[cur][0]);
    const uint8_t* vb = reinterpret_cast<const uint8_t*>(&Vlds[cur][0]);

#pragma unroll
    for (int half = 0; half < 2; ++half) {
      // K A-frags: row = half*32 + kappa, 4 hd-chunks
      bf16x8 kf[4];
      const int krow = half * 32 + kappa;
#pragma unroll
      for (int ks = 0; ks < 4; ++ks)
        kf[ks] = *reinterpret_cast<const bf16x8*>(kb + krow * 128 + koff[ks]);
      // V A-frags: row = 32*hb + q5, keys 16*ks2(+half*32)
      bf16x8 vf[2][2];
#pragma unroll
      for (int hb = 0; hb < 2; ++hb) {
        const int vrow = 32 * hb + q5;
#pragma unroll
        for (int ks2 = 0; ks2 < 2; ++ks2)
          vf[hb][ks2] = *reinterpret_cast<const bf16x8*>(
              vb + vrow * 128 + voff[half][ks2]);
      }

#pragma unroll
      for (int grp = 0; grp < 2; ++grp) {
        // QK^T: D[key32][q32], C-init = -M folds running-max subtraction
        const float negM = -M[grp];
        f32x16 sc;
#pragma unroll
        for (int e = 0; e < 16; ++e) sc[e] = negM;
        __builtin_amdgcn_s_setprio(1);
#pragma unroll
        for (int ks = 0; ks < 4; ++ks)
          sc = __builtin_amdgcn_mfma_f32_32x32x16_bf16(kf[ks], qf[grp][ks], sc,
                                                       0, 0, 0);
        __builtin_amdgcn_s_setprio(0);

        // row max: 15 in-lane + 1 cross (lane pair l <-> l+32)
        float m0 = fmaxf(fmaxf(sc[0], sc[1]), fmaxf(sc[2], sc[3]));
        float m1 = fmaxf(fmaxf(sc[4], sc[5]), fmaxf(sc[6], sc[7]));
        float m2 = fmaxf(fmaxf(sc[8], sc[9]), fmaxf(sc[10], sc[11]));
        float m3 = fmaxf(fmaxf(sc[12], sc[13]), fmaxf(sc[14], sc[15]));
        float mloc = fmaxf(fmaxf(m0, m1), fmaxf(m2, m3));
        mloc = fmaxf(mloc, __shfl_xor(mloc, 32));

        float p[16];
        if (__any(mloc > 8.0f)) {  // defer-max: rescale only on >2^8 growth
          const float delta = fmaxf(mloc, 0.0f);
          const float corr = exp2_hw(-delta);
          M[grp] += delta;
          L[grp] *= corr;
#pragma unroll
          for (int hb = 0; hb < 2; ++hb)
#pragma unroll
            for (int e = 0; e < 16; ++e) ctx[grp][hb][e] *= corr;
#pragma unroll
          for (int e = 0; e < 16; ++e) p[e] = exp2_hw(sc[e] - delta);
        } else {
#pragma unroll
          for (int e = 0; e < 16; ++e) p[e] = exp2_hw(sc[e]);
        }

        L[grp] += ((p[0] + p[1]) + (p[2] + p[3])) +
                  ((p[4] + p[5]) + (p[6] + p[7])) +
                  ((p[8] + p[9]) + (p[10] + p[11])) +
                  ((p[12] + p[13]) + (p[14] + p[15]));

        // pack P: reg r <-> key 16*(r>>3) + 8*hi + (r&7), already B-frag order
        union { uint32_t u[4]; bf16x8 v; } pa0, pa1;
        pa0.u[0] = cvt_pk_bf16(p[0], p[1]);
        pa0.u[1] = cvt_pk_bf16(p[2], p[3]);
        pa0.u[2] = cvt_pk_bf16(p[4], p[5]);
        pa0.u[3] = cvt_pk_bf16(p[6], p[7]);
        pa1.u[0] = cvt_pk_bf16(p[8], p[9]);
        pa1.u[1] = cvt_pk_bf16(p[10], p[11]);
        pa1.u[2] = cvt_pk_bf16(p[12], p[13]);
        pa1.u[3] = cvt_pk_bf16(p[14], p[15]);

        __builtin_amdgcn_s_setprio(1);
#pragma unroll
        for (int hb = 0; hb < 2; ++hb) {
          ctx[grp][hb] = __builtin_amdgcn_mfma_f32_32x32x16_bf16(
              vf[hb][0], pa0.v, ctx[grp][hb], 0, 0, 0);
          ctx[grp][hb] = __builtin_amdgcn_mfma_f32_32x32x16_bf16(
              vf[hb][1], pa1.v, ctx[grp][hb], 0, 0, 0);
        }
        __builtin_amdgcn_s_setprio(0);
      }
    }
  }

  // finalize: L reduce across lane pair, normalize, store
  const int b = bh >> 4, h = bh & 15;
#pragma unroll
  for (int grp = 0; grp < 2; ++grp) {
    float Lt = L[grp] + __shfl_xor(L[grp], 32);
    const float inv = 1.0f / Lt;
    const int s = qrow_base + grp * 32 + q5;
#pragma unroll
    for (int hb = 0; hb < 2; ++hb) {
#pragma unroll
      for (int t = 0; t < 4; ++t) {
        // regs 4t..4t+3 -> hd = 32*hb + 8*t + 4*hi + (0..3)
        uint2 st;
        st.x = cvt_pk_bf16(ctx[grp][hb][4 * t] * inv,
                           ctx[grp][hb][4 * t + 1] * inv);
        st.y = cvt_pk_bf16(ctx[grp][hb][4 * t + 2] * inv,
                           ctx[grp][hb][4 * t + 3] * inv);
        *reinterpret_cast<uint2*>(
            &CTX[((size_t)b * 2048 + s) * 1024 + h * 64 + hb * 32 + t * 8 +
                 hi * 4]) = st;
      }
    }
  }
}

extern "C" void kernel_launch(void* const* d_in, const int* in_sizes, int n_in,
                              void* d_out, int out_size, void* d_ws,
                              size_t ws_size, hipStream_t stream) {
  (void)in_sizes; (void)n_in; (void)out_size; (void)ws_size;
  const float* x = (const float*)d_in[0];
  const float* wq = (const float*)d_in[1];
  const float* bq = (const float*)d_in[2];
  const float* wk = (const float*)d_in[3];
  const float* bk = (const float*)d_in[4];
  const float* wv = (const float*)d_in[5];
  const float* bv = (const float*)d_in[6];
  const float* wo = (const float*)d_in[7];
  const float* bo = (const float*)d_in[8];
  float* out = (float*)d_out;

  // ws layout (88 MB total)
  uint8_t* ws = (uint8_t*)d_ws;
  uint16_t* xb   = (uint16_t*)(ws + 0);                       // 16 MB  x bf16 [8192][1024]
  uint16_t* wqb  = (uint16_t*)(ws + 16777216);                // 2 MB each
  uint16_t* wkb  = (uint16_t*)(ws + 16777216 + 2097152);
  uint16_t* wvb  = (uint16_t*)(ws + 16777216 + 2 * 2097152);
  uint16_t* wob  = (uint16_t*)(ws + 16777216 + 3 * 2097152);
  uint16_t* qws  = (uint16_t*)(ws + 25165824);                // 16 MB [bh][s][hd]
  uint16_t* kws  = (uint16_t*)(ws + 25165824 + 16777216);     // 16 MB [bh][s][hd]
  uint16_t* vtws = (uint16_t*)(ws + 25165824 + 2 * 16777216); // 16 MB [bh][hd][s]
  uint16_t* ctxw = (uint16_t*)(ws + 25165824 + 3 * 16777216); // 16 MB [b][s][1024]

  cvt_f32_bf16<<<8192, 256, 0, stream>>>(x, xb, 2097152);
  cvt_f32_bf16<<<1024, 256, 0, stream>>>(wq, wqb, 262144);
  cvt_f32_bf16<<<1024, 256, 0, stream>>>(wk, wkb, 262144);
  cvt_f32_bf16<<<1024, 256, 0, stream>>>(wv, wvb, 262144);
  cvt_f32_bf16<<<1024, 256, 0, stream>>>(wo, wob, 262144);

  gemm_nt<0><<<dim3(24, 64), 256, 0, stream>>>(
      xb, wqb, wkb, wvb, bq, bk, bv, qws, kws, vtws, nullptr);
  attn_fwd<<<dim3(64, 8), 256, 0, stream>>>(qws, kws, vtws, ctxw);
  gemm_nt<1><<<dim3(8, 64), 256, 0, stream>>>(
      ctxw, wob, nullptr, nullptr, bo, nullptr, nullptr, nullptr, nullptr,
      nullptr, out);
}